// Round 1
// baseline (915.329 us; speedup 1.0000x reference)
//
#include <hip/hip_runtime.h>

// VQ-VAE VectorQuantizer, MI355X fp32 vector implementation.
// Inputs:  d_in[0] = z_e      (16,256,64,64) fp32  = 16777216 floats
//          d_in[1] = embedding (1024,256)    fp32  = 262144 floats
// Output:  d_out   = [ z_q_st flat (16777216) , vq_loss (1) ]  fp32
//
// score_j(x) = ||e_j||^2 - 2 x.e_j   (||x||^2 dropped: constant per pixel)
// z_q_st == z_q numerically (z_e + (z_q - z_e)); loss = 0.25*mean((z_q-z_e)^2)

#define EMBED_DIM 256
#define N_EMBED   1024
#define HW        4096          // 64*64
#define NPIX      65536         // 16*64*64
#define BETA      0.25f

// d_ws float layout:
//  [0]                     loss accumulator
//  [64 .. 64+262144)       e_t[c][j] = -2*emb[j][c]   (256 x 1024)
//  [262208 .. +1024)       norms[j] = sum_c emb[j][c]^2
#define WS_ET_OFF    64
#define WS_NORM_OFF  (64 + EMBED_DIM * N_EMBED)

// ---------------- stage kernels ----------------

__global__ void k_transpose(const float* __restrict__ emb, float* __restrict__ et) {
    int idx = blockIdx.x * blockDim.x + threadIdx.x;   // 0..262143
    int c = idx >> 10;                                 // row of e_t
    int j = idx & 1023;
    et[idx] = -2.0f * emb[j * EMBED_DIM + c];
}

__global__ void k_norms(const float* __restrict__ emb, float* __restrict__ norms,
                        float* __restrict__ loss_acc) {
    int j = blockIdx.x;
    int lane = threadIdx.x;                            // 64 threads
    const float* row = emb + j * EMBED_DIM;
    float s = 0.f;
    #pragma unroll
    for (int r = 0; r < 4; ++r) {
        float v = row[lane + r * 64];
        s += v * v;
    }
    #pragma unroll
    for (int off = 32; off; off >>= 1) s += __shfl_down(s, off, 64);
    if (lane == 0) norms[j] = s;
    if (blockIdx.x == 0 && lane == 0) *loss_acc = 0.f; // zero before main kernel
}

// ---------------- main kernel ----------------

__global__ __launch_bounds__(256, 2)
void k_vq(const float* __restrict__ z, const float* __restrict__ emb,
          const float* __restrict__ et, const float* __restrict__ norms,
          float* __restrict__ out, float* __restrict__ loss_acc)
{
    __shared__ float zt[EMBED_DIM * 64];   // 64 KB, layout [c][px]
    __shared__ float redv[16 * 64];        // [cg][px]
    __shared__ int   redi[16 * 64];
    __shared__ int   widx[64];
    __shared__ float wsum[4];

    const int tid = threadIdx.x;
    const int wg  = blockIdx.x;            // 0..1023
    const int p0  = wg * 64;
    const int b   = p0 >> 12;              // batch (64 | 4096, so uniform in wg)
    const int hw0 = p0 & 4095;
    const float* zbase = z + (size_t)b * (EMBED_DIM * HW) + hw0;

    // ---- stage z tile: zt[c][px], coalesced 16B global reads ----
    {
        const int lane16 = tid & 15;
        const int crow   = tid >> 4;       // 0..15
        #pragma unroll
        for (int r = 0; r < 16; ++r) {
            int c = r * 16 + crow;
            float4 v = *(const float4*)(zbase + (size_t)c * HW + lane16 * 4);
            *(float4*)&zt[c * 64 + lane16 * 4] = v;
        }
    }
    __syncthreads();

    const int pxg = tid & 15;              // 16 pixel-groups of 4
    const int cg  = tid >> 4;              // 16 code-groups of 4

    float bestv[4] = {3.4e38f, 3.4e38f, 3.4e38f, 3.4e38f};
    int   besti[4] = {0, 0, 0, 0};

    for (int chunk = 0; chunk < 16; ++chunk) {
        const int jbase = chunk * 64 + cg * 4;
        float acc[4][4];
        #pragma unroll
        for (int i = 0; i < 4; ++i)
            #pragma unroll
            for (int k = 0; k < 4; ++k) acc[i][k] = 0.f;

        const float* ec = et + jbase;
        #pragma unroll 4
        for (int c = 0; c < EMBED_DIM; ++c) {
            float4 za = *(const float4*)&zt[c * 64 + pxg * 4];
            float4 eb = *(const float4*)(ec + (size_t)c * N_EMBED);
            float zi[4] = {za.x, za.y, za.z, za.w};
            float ek[4] = {eb.x, eb.y, eb.z, eb.w};
            #pragma unroll
            for (int i = 0; i < 4; ++i)
                #pragma unroll
                for (int k = 0; k < 4; ++k)
                    acc[i][k] += zi[i] * ek[k];
        }

        float nn[4];
        #pragma unroll
        for (int k = 0; k < 4; ++k) nn[k] = norms[jbase + k];
        #pragma unroll
        for (int i = 0; i < 4; ++i)
            #pragma unroll
            for (int k = 0; k < 4; ++k) {
                float s = nn[k] + acc[i][k];
                if (s < bestv[i]) { bestv[i] = s; besti[i] = jbase + k; }
            }
    }

    // ---- per-pixel argmin across the 16 code-groups ----
    #pragma unroll
    for (int i = 0; i < 4; ++i) {
        redv[cg * 64 + pxg * 4 + i] = bestv[i];
        redi[cg * 64 + pxg * 4 + i] = besti[i];
    }
    __syncthreads();
    if (tid < 64) {
        const int px = tid;
        float bv = redv[px];
        int   bi = redi[px];
        #pragma unroll
        for (int g = 1; g < 16; ++g) {
            float v = redv[g * 64 + px];
            int   ix = redi[g * 64 + px];
            // strict <, lower index wins ties (jnp.argmin = first minimum)
            if (v < bv || (v == bv && ix < bi)) { bv = v; bi = ix; }
        }
        widx[px] = bi;
    }
    __syncthreads();

    // ---- epilogue: write z_q (== z_q_st) + accumulate loss ----
    const int px = tid & 63;
    const int wv = tid >> 6;               // wave id 0..3, uniform per wave
    const int j  = widx[px];
    const float* qrow = emb + (size_t)j * EMBED_DIM;
    float* obase = out + (size_t)b * (EMBED_DIM * HW) + hw0;

    float lsum = 0.f;
    #pragma unroll 4
    for (int cc = 0; cc < 16; ++cc) {
        const int c0 = wv * 64 + cc * 4;
        float4 q = *(const float4*)(qrow + c0);
        float qv[4] = {q.x, q.y, q.z, q.w};
        #pragma unroll
        for (int k = 0; k < 4; ++k) {
            const int c = c0 + k;
            float zv = zt[c * 64 + px];
            float d = qv[k] - zv;
            lsum += d * d;
            obase[(size_t)c * HW + px] = qv[k];   // lanes=px contiguous: coalesced
        }
    }

    #pragma unroll
    for (int off = 32; off; off >>= 1) lsum += __shfl_down(lsum, off, 64);
    if ((tid & 63) == 0) wsum[wv] = lsum;
    __syncthreads();
    if (tid == 0) atomicAdd(loss_acc, wsum[0] + wsum[1] + wsum[2] + wsum[3]);
}

__global__ void k_final(const float* __restrict__ loss_acc, float* __restrict__ out_loss) {
    *out_loss = (BETA / (float)NPIX / (float)EMBED_DIM) * (*loss_acc);
}

// ---------------- launch ----------------

extern "C" void kernel_launch(void* const* d_in, const int* in_sizes, int n_in,
                              void* d_out, int out_size, void* d_ws, size_t ws_size,
                              hipStream_t stream) {
    const float* z   = (const float*)d_in[0];
    const float* emb = (const float*)d_in[1];
    float* out       = (float*)d_out;
    float* ws        = (float*)d_ws;

    float* loss_acc = ws;
    float* et       = ws + WS_ET_OFF;
    float* norms    = ws + WS_NORM_OFF;

    k_transpose<<<(EMBED_DIM * N_EMBED) / 256, 256, 0, stream>>>(emb, et);
    k_norms<<<N_EMBED, 64, 0, stream>>>(emb, norms, loss_acc);
    k_vq<<<NPIX / 64, 256, 0, stream>>>(z, emb, et, norms, out, loss_acc);
    k_final<<<1, 1, 0, stream>>>(loss_acc, out + NPIX * EMBED_DIM);
}

// Round 2
// 452.158 us; speedup vs baseline: 2.0244x; 2.0244x over previous
//
#include <hip/hip_runtime.h>
#include <hip/hip_bf16.h>

// VQ-VAE VectorQuantizer — MFMA split-bf16 screen + exact fp32 top-2 rescore.
// z_e (16,256,64,64) fp32, embedding (1024,256) fp32.
// dist_j = ||x||^2 - 2 x.e_j + ||e_j||^2 ; argmin over j; ||x||^2 dropped.
// Screen: S = X * (-2E)^T via bf16 split (K=768: xh*eh + xl*eh + xh*el),
// track top-2 per pixel; epilogue rescores both candidates exactly in fp32.

#define EMBED_DIM 256
#define N_EMBED   1024
#define HW        4096
#define NPIX      65536
#define BETA      0.25f

typedef __attribute__((ext_vector_type(8))) short s8v;
typedef __attribute__((ext_vector_type(4))) float f32x4;

// ---------------- new-path workspace layout (float offsets) ----------------
#define NW_LOSS   0
#define NW_NORMS  64                         // 1024 floats
#define NW_CAND   1152                       // 65536 int2 = 131072 floats
#define NW_ES     132352                     // 1024*768 shorts = 393216 floats
#define NW_XS     525568                     // 65536*512 shorts = 16777216 floats
#define NW_END    17302784                   // floats
#define NEED_BYTES ((size_t)NW_END * 4)

// ---------------- fallback (round-1) layout ----------------
#define WS_ET_OFF    64
#define WS_NORM_OFF  (64 + EMBED_DIM * N_EMBED)

static __device__ inline short f2bf(float f) {
    __hip_bfloat16 h = __float2bfloat16(f);
    return *reinterpret_cast<short*>(&h);
}
static __device__ inline float bf2f(short s) {
    __hip_bfloat16 h;
    *reinterpret_cast<short*>(&h) = s;
    return __bfloat162float(h);
}

// ======================= prep kernels =======================

// norms[j] = sum_c emb[j][c]^2 ; also zeroes loss accumulator
__global__ void k_norms(const float* __restrict__ emb, float* __restrict__ norms,
                        float* __restrict__ loss_acc) {
    int j = blockIdx.x;
    int lane = threadIdx.x;
    const float* row = emb + j * EMBED_DIM;
    float s = 0.f;
    #pragma unroll
    for (int r = 0; r < 4; ++r) { float v = row[lane + r * 64]; s += v * v; }
    #pragma unroll
    for (int off = 32; off; off >>= 1) s += __shfl_down(s, off, 64);
    if (lane == 0) norms[j] = s;
    if (blockIdx.x == 0 && lane == 0) *loss_acc = 0.f;
}

// Es_sw[((nb*24 + kb)*64 + lane)*8 + j] : B-fragment order for 16x16x32 bf16.
// B k-blocks: k<256 -> hi(-2e), k<512 -> hi(-2e) (pairs with xl), k>=512 -> lo(-2e)
__global__ void k_prep_e(const float* __restrict__ emb, short* __restrict__ es) {
    int t = blockIdx.x * 256 + threadIdx.x;      // 64*24*64 = 98304 threads
    int lane = t & 63;
    int kb = (t >> 6) % 24;
    int nb = t / (64 * 24);
    int n = nb * 16 + (lane & 15);
    int k0 = kb * 32 + (lane >> 4) * 8;
    short o[8];
    #pragma unroll
    for (int j = 0; j < 8; ++j) {
        int k = k0 + j;
        int c, lo;
        if (k < 256)      { c = k;       lo = 0; }
        else if (k < 512) { c = k - 256; lo = 0; }
        else              { c = k - 512; lo = 1; }
        float e = -2.0f * emb[n * EMBED_DIM + c];
        short hb = f2bf(e);
        o[j] = lo ? f2bf(e - bf2f(hb)) : hb;
    }
    *(s8v*)(es + ((size_t)(nb * 24 + kb) * 64 + lane) * 8) = *(s8v*)o;
}

// Xs_sw[((pb*16 + kb)*64 + lane)*8 + j] : A-fragment order, kb<8 = xh, kb+8 = xl
__global__ void k_prep_x(const float* __restrict__ z, short* __restrict__ xs) {
    int t = blockIdx.x * 256 + threadIdx.x;      // 4096*8*64 = 2097152 threads
    int lane = t & 63;
    int kb = (t >> 6) & 7;
    int pb = t >> 9;
    int px = pb * 16 + (lane & 15);
    int b = px >> 12, hw = px & 4095;
    int c0 = kb * 32 + (lane >> 4) * 8;
    const float* zb = z + (size_t)b * (EMBED_DIM * HW) + hw;
    short oh[8], ol[8];
    #pragma unroll
    for (int j = 0; j < 8; ++j) {
        float v = zb[(size_t)(c0 + j) * HW];
        short hb = f2bf(v);
        oh[j] = hb;
        ol[j] = f2bf(v - bf2f(hb));
    }
    *(s8v*)(xs + ((size_t)(pb * 16 + kb    ) * 64 + lane) * 8) = *(s8v*)oh;
    *(s8v*)(xs + ((size_t)(pb * 16 + kb + 8) * 64 + lane) * 8) = *(s8v*)ol;
}

// ======================= screen kernel =======================

__device__ inline void top2_merge(float& v1, int& i1, float& v2, int& i2,
                                  float w1, int j1, float w2, int j2) {
    bool bw = (w1 < v1) || (w1 == v1 && j1 < i1);
    float nv1 = bw ? w1 : v1;  int ni1 = bw ? j1 : i1;
    float cv  = bw ? v1 : w1;  int ci  = bw ? i1 : j1;   // loser of firsts
    float dv  = bw ? w2 : v2;  int di  = bw ? j2 : i2;   // winner's runner-up
    bool dw = (dv < cv) || (dv == cv && di < ci);
    v2 = dw ? dv : cv; i2 = dw ? di : ci;
    v1 = nv1; i1 = ni1;
}

// Each wave: 32 px (2 row-blocks) x all 1024 codes in 8 chunks of 128.
// No LDS, no barriers: operands pre-swizzled, loads 16B/lane coalesced.
__global__ __launch_bounds__(256, 2)
void k_screen(const short* __restrict__ xs, const short* __restrict__ es,
              const float* __restrict__ norms, int2* __restrict__ cand) {
    const int tid = threadIdx.x;
    const int lane = tid & 63;
    const int wid = blockIdx.x * 4 + (tid >> 6);
    const int pb0 = wid * 2, pb1 = pb0 + 1;

    float v1[8], v2[8]; int i1[8], i2[8];
    #pragma unroll
    for (int s = 0; s < 8; ++s) { v1[s] = 3.4e38f; v2[s] = 3.4e38f; i1[s] = 0; i2[s] = 0; }

    for (int chunk = 0; chunk < 8; ++chunk) {
        const int nbb = chunk * 8;
        f32x4 acc[2][8];
        #pragma unroll
        for (int r = 0; r < 2; ++r)
            #pragma unroll
            for (int c = 0; c < 8; ++c) acc[r][c] = (f32x4){0.f, 0.f, 0.f, 0.f};

        for (int kb = 0; kb < 24; ++kb) {
            const int akb = kb < 16 ? kb : kb - 16;     // A = [xh | xl | xh(fold)]
            s8v a0 = *(const s8v*)(xs + ((size_t)(pb0 * 16 + akb) * 64 + lane) * 8);
            s8v a1 = *(const s8v*)(xs + ((size_t)(pb1 * 16 + akb) * 64 + lane) * 8);
            s8v bb[8];
            #pragma unroll
            for (int c = 0; c < 8; ++c)
                bb[c] = *(const s8v*)(es + ((size_t)((nbb + c) * 24 + kb) * 64 + lane) * 8);
            #pragma unroll
            for (int c = 0; c < 8; ++c) {
                acc[0][c] = __builtin_amdgcn_mfma_f32_16x16x32_bf16(a0, bb[c], acc[0][c], 0, 0, 0);
                acc[1][c] = __builtin_amdgcn_mfma_f32_16x16x32_bf16(a1, bb[c], acc[1][c], 0, 0, 0);
            }
        }

        // C layout: col = lane&15 (code within 16-blk), row = (lane>>4)*4 + reg
        #pragma unroll
        for (int c = 0; c < 8; ++c) {
            const int j = (nbb + c) * 16 + (lane & 15);
            const float nrm = norms[j];
            #pragma unroll
            for (int r = 0; r < 2; ++r)
                #pragma unroll
                for (int q = 0; q < 4; ++q) {
                    const float s = acc[r][c][q] + nrm;
                    const int slot = r * 4 + q;
                    if (s < v1[slot]) { v2[slot] = v1[slot]; i2[slot] = i1[slot];
                                        v1[slot] = s;        i1[slot] = j; }
                    else if (s < v2[slot]) { v2[slot] = s; i2[slot] = j; }
                }
        }
    }

    // reduce across the 16 code-columns (lanes sharing row-group)
    #pragma unroll
    for (int m = 1; m < 16; m <<= 1) {
        #pragma unroll
        for (int s = 0; s < 8; ++s) {
            float w1 = __shfl_xor(v1[s], m, 64);
            int   j1 = __shfl_xor(i1[s], m, 64);
            float w2 = __shfl_xor(v2[s], m, 64);
            int   j2 = __shfl_xor(i2[s], m, 64);
            top2_merge(v1[s], i1[s], v2[s], i2[s], w1, j1, w2, j2);
        }
    }

    if ((lane & 15) == 0) {
        #pragma unroll
        for (int s = 0; s < 8; ++s) {
            const int r = s >> 2, q = s & 3;
            const int px = (r == 0 ? pb0 : pb1) * 16 + (lane >> 4) * 4 + q;
            cand[px] = make_int2(i1[s], i2[s]);
        }
    }
}

// ======================= epilogue =======================

__global__ __launch_bounds__(256, 2)
void k_epi(const float* __restrict__ z, const float* __restrict__ emb,
           const int2* __restrict__ cand, float* __restrict__ out,
           float* __restrict__ loss_acc) {
    __shared__ float zt[64][257];
    __shared__ int   widx[64];
    __shared__ float wsum[4];
    const int tid = threadIdx.x;
    const int px = tid & 63;
    const int wv = tid >> 6;
    const int p0 = blockIdx.x * 64;
    const int b = p0 >> 12, hw0 = p0 & 4095;
    const float* zb = z + (size_t)b * (EMBED_DIM * HW) + hw0;

    // stage z tile transposed: zt[px][c] (pad 257 -> conflict-free both phases)
    for (int i = 0; i < 64; ++i) {
        const int c = wv * 64 + i;
        zt[px][c] = zb[(size_t)c * HW + px];
    }
    __syncthreads();

    // phase 1: exact fp32 distances for both candidates; wave wv owns 16 px
    const int lane = tid & 63;
    for (int t = 0; t < 16; ++t) {
        const int p = wv * 16 + t;
        const int2 cd = cand[p0 + p];
        const int ji[2] = {cd.x, cd.y};
        float d[2];
        #pragma unroll
        for (int s = 0; s < 2; ++s) {
            const float* er = emb + (size_t)ji[s] * EMBED_DIM;
            float part = 0.f;
            #pragma unroll
            for (int r = 0; r < 4; ++r) {
                const int c = lane + r * 64;
                const float df = er[c] - zt[p][c];
                part += df * df;
            }
            #pragma unroll
            for (int off = 32; off; off >>= 1) part += __shfl_down(part, off, 64);
            d[s] = part;
        }
        if (lane == 0)
            widx[p] = (d[1] < d[0] || (d[1] == d[0] && ji[1] < ji[0])) ? ji[1] : ji[0];
    }
    __syncthreads();

    // phase 2: write z_q (coalesced, lanes = px) + loss
    const int j = widx[px];
    const float* qrow = emb + (size_t)j * EMBED_DIM;
    float* ob = out + (size_t)b * (EMBED_DIM * HW) + hw0;
    float lsum = 0.f;
    #pragma unroll 4
    for (int cc = 0; cc < 16; ++cc) {
        const int c0 = wv * 64 + cc * 4;
        float4 q = *(const float4*)(qrow + c0);
        float qv[4] = {q.x, q.y, q.z, q.w};
        #pragma unroll
        for (int k = 0; k < 4; ++k) {
            const int c = c0 + k;
            const float d = qv[k] - zt[px][c];
            lsum += d * d;
            ob[(size_t)c * HW + px] = qv[k];
        }
    }
    #pragma unroll
    for (int off = 32; off; off >>= 1) lsum += __shfl_down(lsum, off, 64);
    if ((tid & 63) == 0) wsum[wv] = lsum;
    __syncthreads();
    if (tid == 0) atomicAdd(loss_acc, wsum[0] + wsum[1] + wsum[2] + wsum[3]);
}

__global__ void k_final(const float* __restrict__ loss_acc, float* __restrict__ out_loss) {
    *out_loss = (BETA / (float)NPIX / (float)EMBED_DIM) * (*loss_acc);
}

// ======================= fallback (round-1 fp32 path) =======================

__global__ void k_transpose(const float* __restrict__ emb, float* __restrict__ et) {
    int idx = blockIdx.x * blockDim.x + threadIdx.x;
    int c = idx >> 10;
    int j = idx & 1023;
    et[idx] = -2.0f * emb[j * EMBED_DIM + c];
}

__global__ __launch_bounds__(256, 2)
void k_vq(const float* __restrict__ z, const float* __restrict__ emb,
          const float* __restrict__ et, const float* __restrict__ norms,
          float* __restrict__ out, float* __restrict__ loss_acc)
{
    __shared__ float zt[EMBED_DIM * 64];
    __shared__ float redv[16 * 64];
    __shared__ int   redi[16 * 64];
    __shared__ int   widx[64];
    __shared__ float wsum[4];
    const int tid = threadIdx.x;
    const int wg  = blockIdx.x;
    const int p0  = wg * 64;
    const int b   = p0 >> 12;
    const int hw0 = p0 & 4095;
    const float* zbase = z + (size_t)b * (EMBED_DIM * HW) + hw0;
    {
        const int lane16 = tid & 15;
        const int crow   = tid >> 4;
        #pragma unroll
        for (int r = 0; r < 16; ++r) {
            int c = r * 16 + crow;
            float4 v = *(const float4*)(zbase + (size_t)c * HW + lane16 * 4);
            *(float4*)&zt[c * 64 + lane16 * 4] = v;
        }
    }
    __syncthreads();
    const int pxg = tid & 15;
    const int cg  = tid >> 4;
    float bestv[4] = {3.4e38f, 3.4e38f, 3.4e38f, 3.4e38f};
    int   besti[4] = {0, 0, 0, 0};
    for (int chunk = 0; chunk < 16; ++chunk) {
        const int jbase = chunk * 64 + cg * 4;
        float acc[4][4];
        #pragma unroll
        for (int i = 0; i < 4; ++i)
            #pragma unroll
            for (int k = 0; k < 4; ++k) acc[i][k] = 0.f;
        const float* ec = et + jbase;
        #pragma unroll 4
        for (int c = 0; c < EMBED_DIM; ++c) {
            float4 za = *(const float4*)&zt[c * 64 + pxg * 4];
            float4 eb = *(const float4*)(ec + (size_t)c * N_EMBED);
            float zi[4] = {za.x, za.y, za.z, za.w};
            float ek[4] = {eb.x, eb.y, eb.z, eb.w};
            #pragma unroll
            for (int i = 0; i < 4; ++i)
                #pragma unroll
                for (int k = 0; k < 4; ++k)
                    acc[i][k] += zi[i] * ek[k];
        }
        float nn[4];
        #pragma unroll
        for (int k = 0; k < 4; ++k) nn[k] = norms[jbase + k];
        #pragma unroll
        for (int i = 0; i < 4; ++i)
            #pragma unroll
            for (int k = 0; k < 4; ++k) {
                float s = nn[k] + acc[i][k];
                if (s < bestv[i]) { bestv[i] = s; besti[i] = jbase + k; }
            }
    }
    #pragma unroll
    for (int i = 0; i < 4; ++i) {
        redv[cg * 64 + pxg * 4 + i] = bestv[i];
        redi[cg * 64 + pxg * 4 + i] = besti[i];
    }
    __syncthreads();
    if (tid < 64) {
        const int px = tid;
        float bv = redv[px];
        int   bi = redi[px];
        #pragma unroll
        for (int g = 1; g < 16; ++g) {
            float v = redv[g * 64 + px];
            int   ix = redi[g * 64 + px];
            if (v < bv || (v == bv && ix < bi)) { bv = v; bi = ix; }
        }
        widx[px] = bi;
    }
    __syncthreads();
    const int px = tid & 63;
    const int wv = tid >> 6;
    const int j  = widx[px];
    const float* qrow = emb + (size_t)j * EMBED_DIM;
    float* obase = out + (size_t)b * (EMBED_DIM * HW) + hw0;
    float lsum = 0.f;
    #pragma unroll 4
    for (int cc = 0; cc < 16; ++cc) {
        const int c0 = wv * 64 + cc * 4;
        float4 q = *(const float4*)(qrow + c0);
        float qv[4] = {q.x, q.y, q.z, q.w};
        #pragma unroll
        for (int k = 0; k < 4; ++k) {
            const int c = c0 + k;
            float zv = zt[c * 64 + px];
            float d = qv[k] - zv;
            lsum += d * d;
            obase[(size_t)c * HW + px] = qv[k];
        }
    }
    #pragma unroll
    for (int off = 32; off; off >>= 1) lsum += __shfl_down(lsum, off, 64);
    if ((tid & 63) == 0) wsum[wv] = lsum;
    __syncthreads();
    if (tid == 0) atomicAdd(loss_acc, wsum[0] + wsum[1] + wsum[2] + wsum[3]);
}

// ======================= launch =======================

extern "C" void kernel_launch(void* const* d_in, const int* in_sizes, int n_in,
                              void* d_out, int out_size, void* d_ws, size_t ws_size,
                              hipStream_t stream) {
    const float* z   = (const float*)d_in[0];
    const float* emb = (const float*)d_in[1];
    float* out       = (float*)d_out;
    float* ws        = (float*)d_ws;

    if (ws_size >= NEED_BYTES) {
        float* loss_acc = ws + NW_LOSS;
        float* norms    = ws + NW_NORMS;
        int2*  cand     = (int2*)(ws + NW_CAND);
        short* es       = (short*)(ws + NW_ES);
        short* xsw      = (short*)(ws + NW_XS);

        k_prep_e<<<384, 256, 0, stream>>>(emb, es);
        k_norms<<<N_EMBED, 64, 0, stream>>>(emb, norms, loss_acc);
        k_prep_x<<<8192, 256, 0, stream>>>(z, xsw);
        k_screen<<<512, 256, 0, stream>>>(xsw, es, norms, cand);
        k_epi<<<1024, 256, 0, stream>>>(z, emb, cand, out, loss_acc);
        k_final<<<1, 1, 0, stream>>>(loss_acc, out + (size_t)NPIX * EMBED_DIM);
    } else {
        // fallback: round-1 fp32 vector path (needs ~1.1 MB)
        float* loss_acc = ws;
        float* et       = ws + WS_ET_OFF;
        float* norms    = ws + WS_NORM_OFF;
        k_transpose<<<(EMBED_DIM * N_EMBED) / 256, 256, 0, stream>>>(emb, et);
        k_norms<<<N_EMBED, 64, 0, stream>>>(emb, norms, loss_acc);
        k_vq<<<NPIX / 64, 256, 0, stream>>>(z, emb, et, norms, out, loss_acc);
        k_final<<<1, 1, 0, stream>>>(loss_acc, out + (size_t)NPIX * EMBED_DIM);
    }
}

// Round 3
// 335.789 us; speedup vs baseline: 2.7259x; 1.3466x over previous
//
#include <hip/hip_runtime.h>
#include <hip/hip_bf16.h>

// VQ-VAE VectorQuantizer — round 3: S^T-oriented MFMA screen (32x32x16 bf16),
// pixel fragments register-resident, codes streamed from L1/L2, norms folded
// into the GEMM as an extra k-block. Exact fp32 top-2 rescore epilogue.
//
// score_j(x) = ||e_j||^2 - 2 x.e_j  (||x||^2 dropped: per-pixel constant).
// Split bf16: -2e = eh + el, x = xh + xl;  x.(-2e) ~ eh.xh + eh.xl + el.xh.
// K layout (48 kb of 16):  kb 0-15: A=eh, B=xh | 16-31: A=eh, B=xl | 32-47: A=el, B=xh
// kb 48 (norm): A[m][0]=norm_hi, A[m][1]=norm_lo, B[0..1][n]=1.

#define EMBED_DIM 256
#define N_EMBED   1024
#define HW        4096
#define NPIX      65536
#define BETA      0.25f

typedef __attribute__((ext_vector_type(8)))  short s8v;
typedef __attribute__((ext_vector_type(4)))  float f32x4;
typedef __attribute__((ext_vector_type(16))) float f32x16;

// ---------------- workspace layout (float offsets) ----------------
#define NW_LOSS   0
#define NW_NORMS  64                          // 1024 floats
#define NW_CAND   1152                        // 65536 int2 = 131072 floats
#define NW_ES2    132224                      // 33*32*64 s8v = 270336 floats
#define NW_XS2    403456                      // 2048*32*64 s8v = 16777216 floats
#define NW_END    17180672
#define NEED_BYTES ((size_t)NW_END * 4)

// fallback (round-1) layout
#define WS_ET_OFF    64
#define WS_NORM_OFF  (64 + EMBED_DIM * N_EMBED)

static __device__ inline short f2bf(float f) {
    __hip_bfloat16 h = __float2bfloat16(f);
    return *reinterpret_cast<short*>(&h);
}
static __device__ inline float bf2f(short s) {
    __hip_bfloat16 h;
    *reinterpret_cast<short*>(&h) = s;
    return __bfloat162float(h);
}

__device__ inline void top2_merge(float& v1, int& i1, float& v2, int& i2,
                                  float w1, int j1, float w2, int j2) {
    bool bw = (w1 < v1) || (w1 == v1 && j1 < i1);
    float nv1 = bw ? w1 : v1;  int ni1 = bw ? j1 : i1;
    float cv  = bw ? v1 : w1;  int ci  = bw ? i1 : j1;
    float dv  = bw ? w2 : v2;  int di  = bw ? j2 : i2;
    bool dw = (dv < cv) || (dv == cv && di < ci);
    v2 = dw ? dv : cv; i2 = dw ? di : ci;
    v1 = nv1; i1 = ni1;
}

// ======================= prep kernels =======================

__global__ void k_norms(const float* __restrict__ emb, float* __restrict__ norms,
                        float* __restrict__ loss_acc) {
    int j = blockIdx.x;
    int lane = threadIdx.x;
    const float* row = emb + j * EMBED_DIM;
    float s = 0.f;
    #pragma unroll
    for (int r = 0; r < 4; ++r) { float v = row[lane + r * 64]; s += v * v; }
    #pragma unroll
    for (int off = 32; off; off >>= 1) s += __shfl_down(s, off, 64);
    if (lane == 0) norms[j] = s;
    if (blockIdx.x == 0 && lane == 0) *loss_acc = 0.f;
}

// es2 frag index t = (akb*32 + cb)*64 + lane ; akb 0-15 = hi(-2e), 16-31 = lo(-2e),
// 32 = norm kb. A layout: m = cb*32 + (lane&31), k = (lane>>5)*8 + j.
__global__ void k_prep_e2(const float* __restrict__ emb, const float* __restrict__ norms,
                          short* __restrict__ es2) {
    int t = blockIdx.x * 256 + threadIdx.x;       // 33*32*64 = 67584
    if (t >= 33 * 32 * 64) return;
    int lane = t & 63;
    int cb   = (t >> 6) & 31;
    int akb  = t >> 11;                           // 0..32
    int m = cb * 32 + (lane & 31);
    int h = lane >> 5;
    short o[8];
    if (akb < 32) {
        int lo  = akb >= 16;
        int kbb = lo ? akb - 16 : akb;
        #pragma unroll
        for (int j = 0; j < 8; ++j) {
            int cidx = kbb * 16 + h * 8 + j;
            float e = -2.0f * emb[m * EMBED_DIM + cidx];
            short hb = f2bf(e);
            o[j] = lo ? f2bf(e - bf2f(hb)) : hb;
        }
    } else {
        float nm = norms[m];
        short nh = f2bf(nm);
        short nl = f2bf(nm - bf2f(nh));
        #pragma unroll
        for (int j = 0; j < 8; ++j) o[j] = 0;
        if (h == 0) { o[0] = nh; o[1] = nl; }
    }
    *(s8v*)(es2 + (size_t)t * 8) = *(s8v*)o;
}

// xs2 frag index ((pb*32 + bkb)*64 + lane) ; bkb 0-15 = xh, 16-31 = xl.
// B layout: n(px) = pb*32 + (lane&31), k = (lane>>5)*8 + j ; c = kb*16 + k.
__global__ void k_prep_x2(const float* __restrict__ z, short* __restrict__ xs2) {
    int t = blockIdx.x * 256 + threadIdx.x;       // 2048*16*64 = 2097152
    int lane = t & 63;
    int kh   = (t >> 6) & 15;
    int pb   = t >> 10;
    int px = pb * 32 + (lane & 31);
    int h  = lane >> 5;
    int b = px >> 12, hw = px & 4095;
    const float* zb = z + (size_t)b * (EMBED_DIM * HW) + hw;
    int c0 = kh * 16 + h * 8;
    short oh[8], ol[8];
    #pragma unroll
    for (int j = 0; j < 8; ++j) {
        float v = zb[(size_t)(c0 + j) * HW];
        short hb = f2bf(v);
        oh[j] = hb;
        ol[j] = f2bf(v - bf2f(hb));
    }
    *(s8v*)(xs2 + ((size_t)(pb * 32 + kh     ) * 64 + lane) * 8) = *(s8v*)oh;
    *(s8v*)(xs2 + ((size_t)(pb * 32 + 16 + kh) * 64 + lane) * 8) = *(s8v*)ol;
}

// ======================= screen kernel =======================
// Wave owns 32 px (B operand, register-resident). Loops 16 chunks of 64 codes
// (2 A code-blocks of 32). acc = 2 x f32x16. Per-lane top-2 (col = px).

__global__ __launch_bounds__(256, 2)
void k_screen2(const short* __restrict__ es2, const short* __restrict__ xs2,
               int2* __restrict__ cand) {
    const int tid  = threadIdx.x;
    const int lane = tid & 63;
    const int wid  = blockIdx.x * 4 + (tid >> 6);     // 0..2047

    // B fragments: this wave's 32 pixels, full split-K (32 frags = 128 VGPRs)
    const s8v* xv = (const s8v*)xs2 + (size_t)wid * 32 * 64 + lane;
    s8v bx[32];
    #pragma unroll
    for (int f = 0; f < 32; ++f) bx[f] = xv[(size_t)f * 64];

    // norm-kb B fragment: B[0][n]=B[1][n]=1
    s8v bn;
    #pragma unroll
    for (int j = 0; j < 8; ++j) bn[j] = 0;
    if (lane < 32) { bn[0] = (short)0x3F80; bn[1] = (short)0x3F80; }

    const s8v* ev = (const s8v*)es2 + lane;
    const int h4 = (lane >> 5) * 4;

    float v1 = 3.4e38f, v2 = 3.4e38f;
    int   i1 = 0,       i2 = 0;

    for (int c = 0; c < 16; ++c) {
        const int cb0 = c * 2, cb1 = cb0 + 1;
        f32x16 acc0, acc1;
        #pragma unroll
        for (int r = 0; r < 16; ++r) { acc0[r] = 0.f; acc1[r] = 0.f; }

        #pragma unroll
        for (int kb = 0; kb < 48; ++kb) {
            const int akb = (kb < 16) ? kb : kb - 16;   // [eh|eh|el]
            const int bkb = (kb < 32) ? kb : kb - 32;   // [xh|xl|xh]
            s8v a0 = ev[(size_t)(akb * 32 + cb0) * 64];
            s8v a1 = ev[(size_t)(akb * 32 + cb1) * 64];
            acc0 = __builtin_amdgcn_mfma_f32_32x32x16_bf16(a0, bx[bkb], acc0, 0, 0, 0);
            acc1 = __builtin_amdgcn_mfma_f32_32x32x16_bf16(a1, bx[bkb], acc1, 0, 0, 0);
        }
        {   // norm kb
            s8v a0 = ev[(size_t)(32 * 32 + cb0) * 64];
            s8v a1 = ev[(size_t)(32 * 32 + cb1) * 64];
            acc0 = __builtin_amdgcn_mfma_f32_32x32x16_bf16(a0, bn, acc0, 0, 0, 0);
            acc1 = __builtin_amdgcn_mfma_f32_32x32x16_bf16(a1, bn, acc1, 0, 0, 0);
        }

        // top-2 update; C/D: col(px) = lane&31, row = (r&3) + 8*(r>>2) + 4*(lane>>5)
        #pragma unroll
        for (int r = 0; r < 16; ++r) {
            const int row = (r & 3) + 8 * (r >> 2) + h4;
            float s0 = acc0[r];
            int   j0 = c * 64 + row;
            if (s0 < v1)      { v2 = v1; i2 = i1; v1 = s0; i1 = j0; }
            else if (s0 < v2) { v2 = s0; i2 = j0; }
            float s1 = acc1[r];
            int   j1 = c * 64 + 32 + row;
            if (s1 < v1)      { v2 = v1; i2 = i1; v1 = s1; i1 = j1; }
            else if (s1 < v2) { v2 = s1; i2 = j1; }
        }
        __syncthreads();   // keep block's 4 waves on the same A-stream (L1 reuse)
    }

    // merge the two k-row halves (lane ^ 32 holds the other 16 rows per block)
    {
        float w1 = __shfl_xor(v1, 32, 64);
        int   j1 = __shfl_xor(i1, 32, 64);
        float w2 = __shfl_xor(v2, 32, 64);
        int   j2 = __shfl_xor(i2, 32, 64);
        top2_merge(v1, i1, v2, i2, w1, j1, w2, j2);
    }
    if (lane < 32) cand[wid * 32 + lane] = make_int2(i1, i2);
}

// ======================= epilogue =======================

__global__ __launch_bounds__(256, 2)
void k_epi(const float* __restrict__ z, const float* __restrict__ emb,
           const int2* __restrict__ cand, float* __restrict__ out,
           float* __restrict__ loss_acc) {
    __shared__ float zt[64][257];
    __shared__ int   widx[64];
    __shared__ float wsum[4];
    const int tid = threadIdx.x;
    const int px = tid & 63;
    const int wv = tid >> 6;
    const int p0 = blockIdx.x * 64;
    const int b = p0 >> 12, hw0 = p0 & 4095;
    const float* zb = z + (size_t)b * (EMBED_DIM * HW) + hw0;

    for (int i = 0; i < 64; ++i) {
        const int c = wv * 64 + i;
        zt[px][c] = zb[(size_t)c * HW + px];
    }
    __syncthreads();

    const int lane = tid & 63;
    for (int t = 0; t < 16; ++t) {
        const int p = wv * 16 + t;
        const int2 cd = cand[p0 + p];
        const int ji[2] = {cd.x, cd.y};
        float d[2];
        #pragma unroll
        for (int s = 0; s < 2; ++s) {
            const float* er = emb + (size_t)ji[s] * EMBED_DIM;
            float part = 0.f;
            #pragma unroll
            for (int r = 0; r < 4; ++r) {
                const int c = lane + r * 64;
                const float df = er[c] - zt[p][c];
                part += df * df;
            }
            #pragma unroll
            for (int off = 32; off; off >>= 1) part += __shfl_down(part, off, 64);
            d[s] = part;
        }
        if (lane == 0)
            widx[p] = (d[1] < d[0] || (d[1] == d[0] && ji[1] < ji[0])) ? ji[1] : ji[0];
    }
    __syncthreads();

    const int j = widx[px];
    const float* qrow = emb + (size_t)j * EMBED_DIM;
    float* ob = out + (size_t)b * (EMBED_DIM * HW) + hw0;
    float lsum = 0.f;
    #pragma unroll 4
    for (int cc = 0; cc < 16; ++cc) {
        const int c0 = wv * 64 + cc * 4;
        float4 q = *(const float4*)(qrow + c0);
        float qv[4] = {q.x, q.y, q.z, q.w};
        #pragma unroll
        for (int k = 0; k < 4; ++k) {
            const int c = c0 + k;
            const float d = qv[k] - zt[px][c];
            lsum += d * d;
            ob[(size_t)c * HW + px] = qv[k];
        }
    }
    #pragma unroll
    for (int off = 32; off; off >>= 1) lsum += __shfl_down(lsum, off, 64);
    if ((tid & 63) == 0) wsum[wv] = lsum;
    __syncthreads();
    if (tid == 0) atomicAdd(loss_acc, wsum[0] + wsum[1] + wsum[2] + wsum[3]);
}

__global__ void k_final(const float* __restrict__ loss_acc, float* __restrict__ out_loss) {
    *out_loss = (BETA / (float)NPIX / (float)EMBED_DIM) * (*loss_acc);
}

// ======================= fallback (round-1 fp32 path) =======================

__global__ void k_transpose(const float* __restrict__ emb, float* __restrict__ et) {
    int idx = blockIdx.x * blockDim.x + threadIdx.x;
    int c = idx >> 10;
    int j = idx & 1023;
    et[idx] = -2.0f * emb[j * EMBED_DIM + c];
}

__global__ __launch_bounds__(256, 2)
void k_vq(const float* __restrict__ z, const float* __restrict__ emb,
          const float* __restrict__ et, const float* __restrict__ norms,
          float* __restrict__ out, float* __restrict__ loss_acc)
{
    __shared__ float zt[EMBED_DIM * 64];
    __shared__ float redv[16 * 64];
    __shared__ int   redi[16 * 64];
    __shared__ int   widx[64];
    __shared__ float wsum[4];
    const int tid = threadIdx.x;
    const int wg  = blockIdx.x;
    const int p0  = wg * 64;
    const int b   = p0 >> 12;
    const int hw0 = p0 & 4095;
    const float* zbase = z + (size_t)b * (EMBED_DIM * HW) + hw0;
    {
        const int lane16 = tid & 15;
        const int crow   = tid >> 4;
        #pragma unroll
        for (int r = 0; r < 16; ++r) {
            int c = r * 16 + crow;
            float4 v = *(const float4*)(zbase + (size_t)c * HW + lane16 * 4);
            *(float4*)&zt[c * 64 + lane16 * 4] = v;
        }
    }
    __syncthreads();
    const int pxg = tid & 15;
    const int cg  = tid >> 4;
    float bestv[4] = {3.4e38f, 3.4e38f, 3.4e38f, 3.4e38f};
    int   besti[4] = {0, 0, 0, 0};
    for (int chunk = 0; chunk < 16; ++chunk) {
        const int jbase = chunk * 64 + cg * 4;
        float acc[4][4];
        #pragma unroll
        for (int i = 0; i < 4; ++i)
            #pragma unroll
            for (int k = 0; k < 4; ++k) acc[i][k] = 0.f;
        const float* ec = et + jbase;
        #pragma unroll 4
        for (int c = 0; c < EMBED_DIM; ++c) {
            float4 za = *(const float4*)&zt[c * 64 + pxg * 4];
            float4 eb = *(const float4*)(ec + (size_t)c * N_EMBED);
            float zi[4] = {za.x, za.y, za.z, za.w};
            float ek[4] = {eb.x, eb.y, eb.z, eb.w};
            #pragma unroll
            for (int i = 0; i < 4; ++i)
                #pragma unroll
                for (int k = 0; k < 4; ++k)
                    acc[i][k] += zi[i] * ek[k];
        }
        float nn[4];
        #pragma unroll
        for (int k = 0; k < 4; ++k) nn[k] = norms[jbase + k];
        #pragma unroll
        for (int i = 0; i < 4; ++i)
            #pragma unroll
            for (int k = 0; k < 4; ++k) {
                float s = nn[k] + acc[i][k];
                if (s < bestv[i]) { bestv[i] = s; besti[i] = jbase + k; }
            }
    }
    #pragma unroll
    for (int i = 0; i < 4; ++i) {
        redv[cg * 64 + pxg * 4 + i] = bestv[i];
        redi[cg * 64 + pxg * 4 + i] = besti[i];
    }
    __syncthreads();
    if (tid < 64) {
        const int px = tid;
        float bv = redv[px];
        int   bi = redi[px];
        #pragma unroll
        for (int g = 1; g < 16; ++g) {
            float v = redv[g * 64 + px];
            int   ix = redi[g * 64 + px];
            if (v < bv || (v == bv && ix < bi)) { bv = v; bi = ix; }
        }
        widx[px] = bi;
    }
    __syncthreads();
    const int px = tid & 63;
    const int wv = tid >> 6;
    const int j  = widx[px];
    const float* qrow = emb + (size_t)j * EMBED_DIM;
    float* obase = out + (size_t)b * (EMBED_DIM * HW) + hw0;
    float lsum = 0.f;
    #pragma unroll 4
    for (int cc = 0; cc < 16; ++cc) {
        const int c0 = wv * 64 + cc * 4;
        float4 q = *(const float4*)(qrow + c0);
        float qv[4] = {q.x, q.y, q.z, q.w};
        #pragma unroll
        for (int k = 0; k < 4; ++k) {
            const int c = c0 + k;
            float zv = zt[c * 64 + px];
            float d = qv[k] - zv;
            lsum += d * d;
            obase[(size_t)c * HW + px] = qv[k];
        }
    }
    #pragma unroll
    for (int off = 32; off; off >>= 1) lsum += __shfl_down(lsum, off, 64);
    if ((tid & 63) == 0) wsum[wv] = lsum;
    __syncthreads();
    if (tid == 0) atomicAdd(loss_acc, wsum[0] + wsum[1] + wsum[2] + wsum[3]);
}

// ======================= launch =======================

extern "C" void kernel_launch(void* const* d_in, const int* in_sizes, int n_in,
                              void* d_out, int out_size, void* d_ws, size_t ws_size,
                              hipStream_t stream) {
    const float* z   = (const float*)d_in[0];
    const float* emb = (const float*)d_in[1];
    float* out       = (float*)d_out;
    float* ws        = (float*)d_ws;

    if (ws_size >= NEED_BYTES) {
        float* loss_acc = ws + NW_LOSS;
        float* norms    = ws + NW_NORMS;
        int2*  cand     = (int2*)(ws + NW_CAND);
        short* es2      = (short*)(ws + NW_ES2);
        short* xs2      = (short*)(ws + NW_XS2);

        k_norms<<<N_EMBED, 64, 0, stream>>>(emb, norms, loss_acc);
        k_prep_e2<<<264, 256, 0, stream>>>(emb, norms, es2);
        k_prep_x2<<<8192, 256, 0, stream>>>(z, xs2);
        k_screen2<<<512, 256, 0, stream>>>(es2, xs2, cand);
        k_epi<<<1024, 256, 0, stream>>>(z, emb, cand, out, loss_acc);
        k_final<<<1, 1, 0, stream>>>(loss_acc, out + (size_t)NPIX * EMBED_DIM);
    } else {
        float* loss_acc = ws;
        float* et       = ws + WS_ET_OFF;
        float* norms    = ws + WS_NORM_OFF;
        k_transpose<<<(EMBED_DIM * N_EMBED) / 256, 256, 0, stream>>>(emb, et);
        k_norms<<<N_EMBED, 64, 0, stream>>>(emb, norms, loss_acc);
        k_vq<<<NPIX / 64, 256, 0, stream>>>(z, emb, et, norms, out, loss_acc);
        k_final<<<1, 1, 0, stream>>>(loss_acc, out + (size_t)NPIX * EMBED_DIM);
    }
}

// Round 4
// 267.966 us; speedup vs baseline: 3.4158x; 1.2531x over previous
//
#include <hip/hip_runtime.h>
#include <hip/hip_bf16.h>

// VQ-VAE VectorQuantizer — round 4: LDS-staged A-stream screen.
// Screen computes S^T = (-2E)*X^T via 32x32x16 bf16 MFMA with 3-term split
// (eh.xh + eh.xl + el.xh) + norms folded as a 33rd k-block; per-lane top-2;
// exact fp32 rescore in the epilogue. Codebook fragments are staged into LDS
// once per block (global_load_lds, double-buffered) and shared by 8 waves.
// Pixel fragments are built in-kernel from z (prep_x kernel eliminated).

#define EMBED_DIM 256
#define N_EMBED   1024
#define HW        4096
#define NPIX      65536
#define BETA      0.25f

typedef __attribute__((ext_vector_type(8)))  short s8v;
typedef __attribute__((ext_vector_type(16))) float f32x16;

// ---------------- workspace layout (float offsets) ----------------
#define NW_LOSS   0     // [0]=loss accum (float), [1]=done counter (int)
#define NW_NORMS  64    // 1024 floats
#define NW_CAND   1152  // 65536 int2
#define NW_ES2    132224 // 33*32*64 s8v = 270336 floats
#define NW_END    402560
#define NEED_BYTES ((size_t)NW_END * 4)

// fallback (round-1) layout
#define WS_ET_OFF    64
#define WS_NORM_OFF  (64 + EMBED_DIM * N_EMBED)

#define CHUNK_BYTES (66 * 1024)   // 33 akb x 2 cb x 1 KB per chunk of 64 codes

static __device__ inline short f2bf(float f) {
    __hip_bfloat16 h = __float2bfloat16(f);
    return *reinterpret_cast<short*>(&h);
}
static __device__ inline float bf2f(short s) {
    __hip_bfloat16 h;
    *reinterpret_cast<short*>(&h) = s;
    return __bfloat162float(h);
}

__device__ inline void top2_merge(float& v1, int& i1, float& v2, int& i2,
                                  float w1, int j1, float w2, int j2) {
    bool bw = (w1 < v1) || (w1 == v1 && j1 < i1);
    float nv1 = bw ? w1 : v1;  int ni1 = bw ? j1 : i1;
    float cv  = bw ? v1 : w1;  int ci  = bw ? i1 : j1;
    float dv  = bw ? w2 : v2;  int di  = bw ? j2 : i2;
    bool dw = (dv < cv) || (dv == cv && di < ci);
    v2 = dw ? dv : cv; i2 = dw ? di : ci;
    v1 = nv1; i1 = ni1;
}

__device__ inline void async16(const void* g, void* s) {
    __builtin_amdgcn_global_load_lds(
        (const __attribute__((address_space(1))) unsigned int*)g,
        (__attribute__((address_space(3))) unsigned int*)s, 16, 0, 0);
}

// ======================= prep kernels =======================

__global__ void k_norms(const float* __restrict__ emb, float* __restrict__ norms,
                        float* __restrict__ loss_acc) {
    int j = blockIdx.x;
    int lane = threadIdx.x;
    const float* row = emb + j * EMBED_DIM;
    float s = 0.f;
    #pragma unroll
    for (int r = 0; r < 4; ++r) { float v = row[lane + r * 64]; s += v * v; }
    #pragma unroll
    for (int off = 32; off; off >>= 1) s += __shfl_down(s, off, 64);
    if (lane == 0) norms[j] = s;
    if (blockIdx.x == 0 && lane == 0) {
        loss_acc[0] = 0.f;
        ((int*)loss_acc)[1] = 0;              // done counter
    }
}

// es2 frag t = (akb*32 + cb)*64 + lane ; akb 0-15 = hi(-2e), 16-31 = lo(-2e),
// 32 = norm kb. A layout: m = cb*32 + (lane&31), k = (lane>>5)*8 + j.
__global__ void k_prep_e2(const float* __restrict__ emb, const float* __restrict__ norms,
                          short* __restrict__ es2) {
    int t = blockIdx.x * 256 + threadIdx.x;       // 33*32*64 = 67584
    if (t >= 33 * 32 * 64) return;
    int lane = t & 63;
    int cb   = (t >> 6) & 31;
    int akb  = t >> 11;                           // 0..32
    int m = cb * 32 + (lane & 31);
    int h = lane >> 5;
    short o[8];
    if (akb < 32) {
        int lo  = akb >= 16;
        int kbb = lo ? akb - 16 : akb;
        #pragma unroll
        for (int j = 0; j < 8; ++j) {
            int cidx = kbb * 16 + h * 8 + j;
            float e = -2.0f * emb[m * EMBED_DIM + cidx];
            short hb = f2bf(e);
            o[j] = lo ? f2bf(e - bf2f(hb)) : hb;
        }
    } else {
        float nm = norms[m];
        short nh = f2bf(nm);
        short nl = f2bf(nm - bf2f(nh));
        #pragma unroll
        for (int j = 0; j < 8; ++j) o[j] = 0;
        if (h == 0) { o[0] = nh; o[1] = nl; }
    }
    *(s8v*)(es2 + (size_t)t * 8) = *(s8v*)o;
}

// ======================= screen kernel =======================
// 512 threads (8 waves), 256 px/block, grid 256. LDS double-buffers the
// per-chunk A fragments (66 KB each). 16 chunks of 64 codes.

__global__ __launch_bounds__(512, 2)
void k_screen3(const float* __restrict__ z, const short* __restrict__ es2,
               int2* __restrict__ cand) {
    __shared__ __align__(16) char abuf[2 * CHUNK_BYTES];   // 132 KB

    const int tid  = threadIdx.x;
    const int lane = tid & 63;
    const int wv   = tid >> 6;                    // 0..7
    const int pxl  = lane & 31;
    const int h    = lane >> 5;
    const int ln16 = lane * 16;

    // ---- kick off staging of chunk 0 while we build pixel fragments ----
    {
        char* bufn = abuf;
        for (int f = wv; f < 66; f += 8) {
            const short* src = es2 + ((size_t)((f >> 1) * 32 + (f & 1)) * 64 + lane) * 8;
            async16(src, bufn + f * 1024 + ln16);
        }
    }

    // ---- build B fragments (this wave's 32 pixels) straight from z ----
    const int px = blockIdx.x * 256 + wv * 32 + pxl;
    const int b = px >> 12, hw = px & 4095;
    const float* zb = z + (size_t)b * (EMBED_DIM * HW) + hw;

    s8v bx[32];                                   // [0..15]=xh, [16..31]=xl
    #pragma unroll
    for (int kh = 0; kh < 16; ++kh) {
        const int c0 = kh * 16 + h * 8;
        short oh[8], ol[8];
        #pragma unroll
        for (int j = 0; j < 8; ++j) {
            float v = zb[(size_t)(c0 + j) * HW];
            short hb = f2bf(v);
            oh[j] = hb;
            ol[j] = f2bf(v - bf2f(hb));
        }
        bx[kh]      = *(s8v*)oh;
        bx[16 + kh] = *(s8v*)ol;
    }

    s8v bn;                                       // norm-kb B: B[0..1][n] = 1
    #pragma unroll
    for (int j = 0; j < 8; ++j) bn[j] = 0;
    if (lane < 32) { bn[0] = (short)0x3F80; bn[1] = (short)0x3F80; }

    const int h4 = h * 4;
    float v1 = 3.4e38f, v2 = 3.4e38f;
    int   i1 = 0,       i2 = 0;

    __syncthreads();                              // chunk-0 staging complete

    for (int c = 0; c < 16; ++c) {
        // stage chunk c+1 into the other buffer (overlaps with compute)
        if (c + 1 < 16) {
            char* bufn = abuf + ((c + 1) & 1) * CHUNK_BYTES;
            for (int f = wv; f < 66; f += 8) {
                const short* src = es2 +
                    ((size_t)((f >> 1) * 32 + (c + 1) * 2 + (f & 1)) * 64 + lane) * 8;
                async16(src, bufn + f * 1024 + ln16);
            }
        }

        const char* bufc = abuf + (c & 1) * CHUNK_BYTES;
        f32x16 acc0, acc1;
        #pragma unroll
        for (int r = 0; r < 16; ++r) { acc0[r] = 0.f; acc1[r] = 0.f; }

        // eh rows (akb 0..15): x2 reuse against xh and xl
        #pragma unroll
        for (int akb = 0; akb < 16; ++akb) {
            s8v a0 = *(const s8v*)(bufc + (akb * 2 + 0) * 1024 + ln16);
            s8v a1 = *(const s8v*)(bufc + (akb * 2 + 1) * 1024 + ln16);
            acc0 = __builtin_amdgcn_mfma_f32_32x32x16_bf16(a0, bx[akb], acc0, 0, 0, 0);
            acc1 = __builtin_amdgcn_mfma_f32_32x32x16_bf16(a1, bx[akb], acc1, 0, 0, 0);
            acc0 = __builtin_amdgcn_mfma_f32_32x32x16_bf16(a0, bx[16 + akb], acc0, 0, 0, 0);
            acc1 = __builtin_amdgcn_mfma_f32_32x32x16_bf16(a1, bx[16 + akb], acc1, 0, 0, 0);
        }
        // el rows (akb 16..31): against xh
        #pragma unroll
        for (int akb = 16; akb < 32; ++akb) {
            s8v a0 = *(const s8v*)(bufc + (akb * 2 + 0) * 1024 + ln16);
            s8v a1 = *(const s8v*)(bufc + (akb * 2 + 1) * 1024 + ln16);
            acc0 = __builtin_amdgcn_mfma_f32_32x32x16_bf16(a0, bx[akb - 16], acc0, 0, 0, 0);
            acc1 = __builtin_amdgcn_mfma_f32_32x32x16_bf16(a1, bx[akb - 16], acc1, 0, 0, 0);
        }
        // norm kb
        {
            s8v a0 = *(const s8v*)(bufc + 64 * 1024 + ln16);
            s8v a1 = *(const s8v*)(bufc + 65 * 1024 + ln16);
            acc0 = __builtin_amdgcn_mfma_f32_32x32x16_bf16(a0, bn, acc0, 0, 0, 0);
            acc1 = __builtin_amdgcn_mfma_f32_32x32x16_bf16(a1, bn, acc1, 0, 0, 0);
        }

        // top-2 update; C/D: col(px)=lane&31, row=(r&3)+8*(r>>2)+4*(lane>>5)
        #pragma unroll
        for (int r = 0; r < 16; ++r) {
            const int row = (r & 3) + 8 * (r >> 2) + h4;
            float s0 = acc0[r];
            int   j0 = c * 64 + row;
            if (s0 < v1)      { v2 = v1; i2 = i1; v1 = s0; i1 = j0; }
            else if (s0 < v2) { v2 = s0; i2 = j0; }
            float s1 = acc1[r];
            int   j1 = c * 64 + 32 + row;
            if (s1 < v1)      { v2 = v1; i2 = i1; v1 = s1; i1 = j1; }
            else if (s1 < v2) { v2 = s1; i2 = j1; }
        }

        __syncthreads();   // drains staging vmcnt; guards buffer reuse
    }

    // merge the two k-row halves (lane^32 holds the other 16 rows per block)
    {
        float w1 = __shfl_xor(v1, 32, 64);
        int   j1 = __shfl_xor(i1, 32, 64);
        float w2 = __shfl_xor(v2, 32, 64);
        int   j2 = __shfl_xor(i2, 32, 64);
        top2_merge(v1, i1, v2, i2, w1, j1, w2, j2);
    }
    if (lane < 32) cand[px] = make_int2(i1, i2);
}

// ======================= epilogue (fused final) =======================

__global__ __launch_bounds__(256, 2)
void k_epi(const float* __restrict__ z, const float* __restrict__ emb,
           const int2* __restrict__ cand, float* __restrict__ out,
           float* __restrict__ loss_acc, float* __restrict__ out_loss) {
    __shared__ float zt[64][257];
    __shared__ int   widx[64];
    __shared__ float wsum[4];
    const int tid = threadIdx.x;
    const int px = tid & 63;
    const int wv = tid >> 6;
    const int p0 = blockIdx.x * 64;
    const int b = p0 >> 12, hw0 = p0 & 4095;
    const float* zb = z + (size_t)b * (EMBED_DIM * HW) + hw0;

    for (int i = 0; i < 64; ++i) {
        const int c = wv * 64 + i;
        zt[px][c] = zb[(size_t)c * HW + px];
    }
    __syncthreads();

    const int lane = tid & 63;
    for (int t = 0; t < 16; ++t) {
        const int p = wv * 16 + t;
        const int2 cd = cand[p0 + p];
        const int ji[2] = {cd.x, cd.y};
        float d[2];
        #pragma unroll
        for (int s = 0; s < 2; ++s) {
            const float* er = emb + (size_t)ji[s] * EMBED_DIM;
            float part = 0.f;
            #pragma unroll
            for (int r = 0; r < 4; ++r) {
                const int c = lane + r * 64;
                const float df = er[c] - zt[p][c];
                part += df * df;
            }
            #pragma unroll
            for (int off = 32; off; off >>= 1) part += __shfl_down(part, off, 64);
            d[s] = part;
        }
        if (lane == 0)
            widx[p] = (d[1] < d[0] || (d[1] == d[0] && ji[1] < ji[0])) ? ji[1] : ji[0];
    }
    __syncthreads();

    const int j = widx[px];
    const float* qrow = emb + (size_t)j * EMBED_DIM;
    float* ob = out + (size_t)b * (EMBED_DIM * HW) + hw0;
    float lsum = 0.f;
    #pragma unroll 4
    for (int cc = 0; cc < 16; ++cc) {
        const int c0 = wv * 64 + cc * 4;
        float4 q = *(const float4*)(qrow + c0);
        float qv[4] = {q.x, q.y, q.z, q.w};
        #pragma unroll
        for (int k = 0; k < 4; ++k) {
            const int c = c0 + k;
            const float d = qv[k] - zt[px][c];
            lsum += d * d;
            ob[(size_t)c * HW + px] = qv[k];
        }
    }
    #pragma unroll
    for (int off = 32; off; off >>= 1) lsum += __shfl_down(lsum, off, 64);
    if ((tid & 63) == 0) wsum[wv] = lsum;
    __syncthreads();
    if (tid == 0) {
        atomicAdd(loss_acc, wsum[0] + wsum[1] + wsum[2] + wsum[3]);
        __threadfence();
        int* done = (int*)loss_acc + 1;
        int old = atomicAdd(done, 1);
        if (old == (int)gridDim.x - 1) {
            float total = atomicAdd(loss_acc, 0.0f);   // device-scope read
            *out_loss = (BETA / (float)NPIX / (float)EMBED_DIM) * total;
        }
    }
}

__global__ void k_final(const float* __restrict__ loss_acc, float* __restrict__ out_loss) {
    *out_loss = (BETA / (float)NPIX / (float)EMBED_DIM) * (*loss_acc);
}

// ======================= fallback (round-1 fp32 path) =======================

__global__ void k_transpose(const float* __restrict__ emb, float* __restrict__ et) {
    int idx = blockIdx.x * blockDim.x + threadIdx.x;
    int c = idx >> 10;
    int j = idx & 1023;
    et[idx] = -2.0f * emb[j * EMBED_DIM + c];
}

__global__ __launch_bounds__(256, 2)
void k_vq(const float* __restrict__ z, const float* __restrict__ emb,
          const float* __restrict__ et, const float* __restrict__ norms,
          float* __restrict__ out, float* __restrict__ loss_acc)
{
    __shared__ float zt[EMBED_DIM * 64];
    __shared__ float redv[16 * 64];
    __shared__ int   redi[16 * 64];
    __shared__ int   widx[64];
    __shared__ float wsum[4];
    const int tid = threadIdx.x;
    const int wg  = blockIdx.x;
    const int p0  = wg * 64;
    const int b   = p0 >> 12;
    const int hw0 = p0 & 4095;
    const float* zbase = z + (size_t)b * (EMBED_DIM * HW) + hw0;
    {
        const int lane16 = tid & 15;
        const int crow   = tid >> 4;
        #pragma unroll
        for (int r = 0; r < 16; ++r) {
            int c = r * 16 + crow;
            float4 v = *(const float4*)(zbase + (size_t)c * HW + lane16 * 4);
            *(float4*)&zt[c * 64 + lane16 * 4] = v;
        }
    }
    __syncthreads();
    const int pxg = tid & 15;
    const int cg  = tid >> 4;
    float bestv[4] = {3.4e38f, 3.4e38f, 3.4e38f, 3.4e38f};
    int   besti[4] = {0, 0, 0, 0};
    for (int chunk = 0; chunk < 16; ++chunk) {
        const int jbase = chunk * 64 + cg * 4;
        float acc[4][4];
        #pragma unroll
        for (int i = 0; i < 4; ++i)
            #pragma unroll
            for (int k = 0; k < 4; ++k) acc[i][k] = 0.f;
        const float* ec = et + jbase;
        #pragma unroll 4
        for (int c = 0; c < EMBED_DIM; ++c) {
            float4 za = *(const float4*)&zt[c * 64 + pxg * 4];
            float4 eb = *(const float4*)(ec + (size_t)c * N_EMBED);
            float zi[4] = {za.x, za.y, za.z, za.w};
            float ek[4] = {eb.x, eb.y, eb.z, eb.w};
            #pragma unroll
            for (int i = 0; i < 4; ++i)
                #pragma unroll
                for (int k = 0; k < 4; ++k)
                    acc[i][k] += zi[i] * ek[k];
        }
        float nn[4];
        #pragma unroll
        for (int k = 0; k < 4; ++k) nn[k] = norms[jbase + k];
        #pragma unroll
        for (int i = 0; i < 4; ++i)
            #pragma unroll
            for (int k = 0; k < 4; ++k) {
                float s = nn[k] + acc[i][k];
                if (s < bestv[i]) { bestv[i] = s; besti[i] = jbase + k; }
            }
    }
    #pragma unroll
    for (int i = 0; i < 4; ++i) {
        redv[cg * 64 + pxg * 4 + i] = bestv[i];
        redi[cg * 64 + pxg * 4 + i] = besti[i];
    }
    __syncthreads();
    if (tid < 64) {
        const int px2 = tid;
        float bv = redv[px2];
        int   bi = redi[px2];
        #pragma unroll
        for (int g = 1; g < 16; ++g) {
            float v = redv[g * 64 + px2];
            int   ix = redi[g * 64 + px2];
            if (v < bv || (v == bv && ix < bi)) { bv = v; bi = ix; }
        }
        widx[px2] = bi;
    }
    __syncthreads();
    const int px = tid & 63;
    const int wv = tid >> 6;
    const int j  = widx[px];
    const float* qrow = emb + (size_t)j * EMBED_DIM;
    float* obase = out + (size_t)b * (EMBED_DIM * HW) + hw0;
    float lsum = 0.f;
    #pragma unroll 4
    for (int cc = 0; cc < 16; ++cc) {
        const int c0 = wv * 64 + cc * 4;
        float4 q = *(const float4*)(qrow + c0);
        float qv[4] = {q.x, q.y, q.z, q.w};
        #pragma unroll
        for (int k = 0; k < 4; ++k) {
            const int c = c0 + k;
            float zv = zt[c * 64 + px];
            float d = qv[k] - zv;
            lsum += d * d;
            obase[(size_t)c * HW + px] = qv[k];
        }
    }
    #pragma unroll
    for (int off = 32; off; off >>= 1) lsum += __shfl_down(lsum, off, 64);
    if ((tid & 63) == 0) wsum[wv] = lsum;
    __syncthreads();
    if (tid == 0) atomicAdd(loss_acc, wsum[0] + wsum[1] + wsum[2] + wsum[3]);
}

// ======================= launch =======================

extern "C" void kernel_launch(void* const* d_in, const int* in_sizes, int n_in,
                              void* d_out, int out_size, void* d_ws, size_t ws_size,
                              hipStream_t stream) {
    const float* z   = (const float*)d_in[0];
    const float* emb = (const float*)d_in[1];
    float* out       = (float*)d_out;
    float* ws        = (float*)d_ws;

    if (ws_size >= NEED_BYTES) {
        float* loss_acc = ws + NW_LOSS;
        float* norms    = ws + NW_NORMS;
        int2*  cand     = (int2*)(ws + NW_CAND);
        short* es2      = (short*)(ws + NW_ES2);

        k_norms<<<N_EMBED, 64, 0, stream>>>(emb, norms, loss_acc);
        k_prep_e2<<<264, 256, 0, stream>>>(emb, norms, es2);
        k_screen3<<<256, 512, 0, stream>>>(z, es2, cand);
        k_epi<<<1024, 256, 0, stream>>>(z, emb, cand, out, loss_acc,
                                        out + (size_t)NPIX * EMBED_DIM);
    } else {
        float* loss_acc = ws;
        float* et       = ws + WS_ET_OFF;
        float* norms    = ws + WS_NORM_OFF;
        k_transpose<<<(EMBED_DIM * N_EMBED) / 256, 256, 0, stream>>>(emb, et);
        k_norms<<<N_EMBED, 64, 0, stream>>>(emb, norms, loss_acc);
        k_vq<<<NPIX / 64, 256, 0, stream>>>(z, emb, et, norms, out, loss_acc);
        k_final<<<1, 1, 0, stream>>>(loss_acc, out + (size_t)NPIX * EMBED_DIM);
    }
}

// Round 5
// 231.760 us; speedup vs baseline: 3.9495x; 1.1562x over previous
//
#include <hip/hip_runtime.h>
#include <hip/hip_bf16.h>

// VQ-VAE VectorQuantizer — round 5: fp16 2-term screen + top-4 exact rescore.
// Screen computes S^T = (-2E)*X^T via 32x32x16 f16 MFMA:
//   x = xh + xl (fp16 hi/lo), e single fp16  ->  K = 2*256 + norm-kb.
//   norms folded as 17th k-block (hi/lo in k=0,1 vs B=ones).
// Per-lane top-4, exact fp32 rescore of 4 candidates in epilogue.
// Codebook fragments staged into LDS per block (global_load_lds, dbuf).

#define EMBED_DIM 256
#define N_EMBED   1024
#define HW        4096
#define NPIX      65536
#define BETA      0.25f

typedef _Float16 h8v __attribute__((ext_vector_type(8)));
typedef __attribute__((ext_vector_type(16))) float f32x16;

// ---------------- workspace layout (float offsets) ----------------
#define NW_LOSS   0       // [0] = loss accumulator
#define NW_NORMS  64      // 1024 floats
#define NW_CAND   1152    // 65536 int4 = 262144 floats
#define NW_ES2    263296  // 17*32*64 h8v = 278528 halves = 139264 floats
#define NW_END    402560
#define NEED_BYTES ((size_t)NW_END * 4)

// fallback (round-1) layout
#define WS_ET_OFF    64
#define WS_NORM_OFF  (64 + EMBED_DIM * N_EMBED)

#define CHUNK_BYTES (34 * 1024)   // 17 akb x 2 cb x 1 KB per chunk of 64 codes

__device__ inline void async16(const void* g, void* s) {
    __builtin_amdgcn_global_load_lds(
        (const __attribute__((address_space(1))) unsigned int*)g,
        (__attribute__((address_space(3))) unsigned int*)s, 16, 0, 0);
}

// branchless sorted top-4 insert (ties resolved later by exact rescore)
__device__ inline void top4_ins(float s, int j, float v[4], int id[4]) {
    bool b0 = s < v[0];
    bool b1 = s < v[1];
    bool b2 = s < v[2];
    bool b3 = s < v[3];
    v[3] = b2 ? v[2] : (b3 ? s : v[3]);  id[3] = b2 ? id[2] : (b3 ? j : id[3]);
    v[2] = b1 ? v[1] : (b2 ? s : v[2]);  id[2] = b1 ? id[1] : (b2 ? j : id[2]);
    v[1] = b0 ? v[0] : (b1 ? s : v[1]);  id[1] = b0 ? id[0] : (b1 ? j : id[1]);
    v[0] = b0 ? s : v[0];                id[0] = b0 ? j : id[0];
}

// ======================= prep kernels =======================

__global__ void k_norms(const float* __restrict__ emb, float* __restrict__ norms,
                        float* __restrict__ loss_acc) {
    int j = blockIdx.x;
    int lane = threadIdx.x;
    const float* row = emb + j * EMBED_DIM;
    float s = 0.f;
    #pragma unroll
    for (int r = 0; r < 4; ++r) { float v = row[lane + r * 64]; s += v * v; }
    #pragma unroll
    for (int off = 32; off; off >>= 1) s += __shfl_down(s, off, 64);
    if (lane == 0) norms[j] = s;
    if (blockIdx.x == 0 && lane == 0) loss_acc[0] = 0.f;
}

// es2 frag t = (akb*32 + cb)*64 + lane ; akb 0-15 = fp16(-2e), 16 = norm kb.
// A layout: m = cb*32 + (lane&31), k = (lane>>5)*8 + j ; c = akb*16 + k.
__global__ void k_prep_e2(const float* __restrict__ emb, const float* __restrict__ norms,
                          _Float16* __restrict__ es2) {
    int t = blockIdx.x * 256 + threadIdx.x;       // 17*32*64 = 34816
    if (t >= 17 * 32 * 64) return;
    int lane = t & 63;
    int cb   = (t >> 6) & 31;
    int akb  = t >> 11;                           // 0..16
    int m = cb * 32 + (lane & 31);
    int h = lane >> 5;
    _Float16 o[8];
    if (akb < 16) {
        #pragma unroll
        for (int j = 0; j < 8; ++j) {
            int c = akb * 16 + h * 8 + j;
            o[j] = (_Float16)(-2.0f * emb[m * EMBED_DIM + c]);
        }
    } else {
        float nm = norms[m];
        _Float16 nh = (_Float16)nm;
        _Float16 nl = (_Float16)(nm - (float)nh);
        #pragma unroll
        for (int j = 0; j < 8; ++j) o[j] = (_Float16)0.f;
        if (h == 0) { o[0] = nh; o[1] = nl; }
    }
    *(h8v*)(es2 + (size_t)t * 8) = *(h8v*)o;
}

// ======================= screen kernel =======================
// 512 threads (8 waves), 256 px/block, grid 256. LDS double-buffers the
// per-chunk A fragments (34 KB each). 16 chunks of 64 codes.

__global__ __launch_bounds__(512, 2)
void k_screen4(const float* __restrict__ z, const _Float16* __restrict__ es2,
               int4* __restrict__ cand) {
    __shared__ __align__(16) char abuf[2 * CHUNK_BYTES];   // 68 KB

    const int tid  = threadIdx.x;
    const int lane = tid & 63;
    const int wv   = tid >> 6;                    // 0..7
    const int pxl  = lane & 31;
    const int h    = lane >> 5;
    const int ln16 = lane * 16;

    // kick off staging of chunk 0
    {
        char* bufn = abuf;
        for (int f = wv; f < 34; f += 8) {
            const _Float16* src = es2 + ((size_t)((f >> 1) * 32 + (f & 1)) * 64 + lane) * 8;
            async16(src, bufn + f * 1024 + ln16);
        }
    }

    // build B fragments (this wave's 32 pixels) straight from z
    const int px = blockIdx.x * 256 + wv * 32 + pxl;
    const int b = px >> 12, hw = px & 4095;
    const float* zb = z + (size_t)b * (EMBED_DIM * HW) + hw;

    h8v bx[32];                                   // [0..15]=xh, [16..31]=xl
    #pragma unroll
    for (int kh = 0; kh < 16; ++kh) {
        const int c0 = kh * 16 + h * 8;
        _Float16 oh[8], ol[8];
        #pragma unroll
        for (int j = 0; j < 8; ++j) {
            float v = zb[(size_t)(c0 + j) * HW];
            _Float16 hv = (_Float16)v;
            oh[j] = hv;
            ol[j] = (_Float16)(v - (float)hv);
        }
        bx[kh]      = *(h8v*)oh;
        bx[16 + kh] = *(h8v*)ol;
    }

    h8v bn;                                       // norm-kb B: B[0..1][n] = 1
    #pragma unroll
    for (int j = 0; j < 8; ++j) bn[j] = (_Float16)0.f;
    if (lane < 32) { bn[0] = (_Float16)1.f; bn[1] = (_Float16)1.f; }

    const int h4 = h * 4;
    float v[4]  = {3.4e38f, 3.4e38f, 3.4e38f, 3.4e38f};
    int   id[4] = {0, 0, 0, 0};

    __syncthreads();                              // chunk-0 staging complete

    for (int c = 0; c < 16; ++c) {
        if (c + 1 < 16) {                         // stage next chunk (overlapped)
            char* bufn = abuf + ((c + 1) & 1) * CHUNK_BYTES;
            for (int f = wv; f < 34; f += 8) {
                const _Float16* src = es2 +
                    ((size_t)((f >> 1) * 32 + (c + 1) * 2 + (f & 1)) * 64 + lane) * 8;
                async16(src, bufn + f * 1024 + ln16);
            }
        }

        const char* bufc = abuf + (c & 1) * CHUNK_BYTES;
        f32x16 acc0, acc1;
        #pragma unroll
        for (int r = 0; r < 16; ++r) { acc0[r] = 0.f; acc1[r] = 0.f; }

        // software-pipelined A-frag loads: prefetch akb+1 while computing akb
        h8v a0 = *(const h8v*)(bufc + 0 * 1024 + ln16);
        h8v a1 = *(const h8v*)(bufc + 1 * 1024 + ln16);
        #pragma unroll
        for (int akb = 0; akb < 16; ++akb) {
            h8v n0 = *(const h8v*)(bufc + ((akb + 1) * 2 + 0) * 1024 + ln16);
            h8v n1 = *(const h8v*)(bufc + ((akb + 1) * 2 + 1) * 1024 + ln16);
            acc0 = __builtin_amdgcn_mfma_f32_32x32x16_f16(a0, bx[akb], acc0, 0, 0, 0);
            acc1 = __builtin_amdgcn_mfma_f32_32x32x16_f16(a1, bx[akb], acc1, 0, 0, 0);
            acc0 = __builtin_amdgcn_mfma_f32_32x32x16_f16(a0, bx[16 + akb], acc0, 0, 0, 0);
            acc1 = __builtin_amdgcn_mfma_f32_32x32x16_f16(a1, bx[16 + akb], acc1, 0, 0, 0);
            a0 = n0; a1 = n1;
        }
        // norm kb (akb == 16)
        acc0 = __builtin_amdgcn_mfma_f32_32x32x16_f16(a0, bn, acc0, 0, 0, 0);
        acc1 = __builtin_amdgcn_mfma_f32_32x32x16_f16(a1, bn, acc1, 0, 0, 0);

        // top-4 update; C/D: col(px)=lane&31, row=(r&3)+8*(r>>2)+4*(lane>>5)
        #pragma unroll
        for (int r = 0; r < 16; ++r) {
            const int row = (r & 3) + 8 * (r >> 2) + h4;
            top4_ins(acc0[r], c * 64 + row,      v, id);
            top4_ins(acc1[r], c * 64 + 32 + row, v, id);
        }

        __syncthreads();   // drains staging; guards buffer reuse
    }

    // merge the two k-row halves (lane^32 holds the other 16 rows per block)
    #pragma unroll
    for (int t = 0; t < 4; ++t) {
        float w  = __shfl_xor(v[t], 32, 64);
        int   wj = __shfl_xor(id[t], 32, 64);
        top4_ins(w, wj, v, id);
    }
    if (lane < 32) cand[px] = make_int4(id[0], id[1], id[2], id[3]);
}

// ======================= epilogue =======================

__global__ __launch_bounds__(256, 2)
void k_epi(const float* __restrict__ z, const float* __restrict__ emb,
           const int4* __restrict__ cand, float* __restrict__ out,
           float* __restrict__ loss_acc) {
    __shared__ float zt[64][257];
    __shared__ int   widx[64];
    __shared__ float wsum[4];
    const int tid = threadIdx.x;
    const int px = tid & 63;
    const int wv = tid >> 6;
    const int p0 = blockIdx.x * 64;
    const int b = p0 >> 12, hw0 = p0 & 4095;
    const float* zb = z + (size_t)b * (EMBED_DIM * HW) + hw0;

    for (int i = 0; i < 64; ++i) {
        const int c = wv * 64 + i;
        zt[px][c] = zb[(size_t)c * HW + px];
    }
    __syncthreads();

    const int lane = tid & 63;
    for (int t = 0; t < 16; ++t) {
        const int p = wv * 16 + t;
        const int4 cd = cand[p0 + p];
        const int ji[4] = {cd.x, cd.y, cd.z, cd.w};
        float part[4];
        #pragma unroll
        for (int s = 0; s < 4; ++s) {
            const float* er = emb + (size_t)ji[s] * EMBED_DIM;
            float acc = 0.f;
            #pragma unroll
            for (int r = 0; r < 4; ++r) {
                const int c = lane + r * 64;
                const float df = er[c] - zt[p][c];
                acc += df * df;
            }
            part[s] = acc;
        }
        #pragma unroll
        for (int s = 0; s < 4; ++s) {
            #pragma unroll
            for (int off = 32; off; off >>= 1) part[s] += __shfl_down(part[s], off, 64);
        }
        if (lane == 0) {
            float bd = part[0]; int bj = ji[0];
            #pragma unroll
            for (int s = 1; s < 4; ++s)
                if (part[s] < bd || (part[s] == bd && ji[s] < bj)) { bd = part[s]; bj = ji[s]; }
            widx[p] = bj;
        }
    }
    __syncthreads();

    const int j = widx[px];
    const float* qrow = emb + (size_t)j * EMBED_DIM;
    float* ob = out + (size_t)b * (EMBED_DIM * HW) + hw0;
    float lsum = 0.f;
    #pragma unroll 4
    for (int cc = 0; cc < 16; ++cc) {
        const int c0 = wv * 64 + cc * 4;
        float4 q = *(const float4*)(qrow + c0);
        float qv[4] = {q.x, q.y, q.z, q.w};
        #pragma unroll
        for (int k = 0; k < 4; ++k) {
            const int c = c0 + k;
            const float d = qv[k] - zt[px][c];
            lsum += d * d;
            ob[(size_t)c * HW + px] = qv[k];
        }
    }
    #pragma unroll
    for (int off = 32; off; off >>= 1) lsum += __shfl_down(lsum, off, 64);
    if ((tid & 63) == 0) wsum[wv] = lsum;
    __syncthreads();
    if (tid == 0) atomicAdd(loss_acc, wsum[0] + wsum[1] + wsum[2] + wsum[3]);
}

__global__ void k_final(const float* __restrict__ loss_acc, float* __restrict__ out_loss) {
    *out_loss = (BETA / (float)NPIX / (float)EMBED_DIM) * (*loss_acc);
}

// ======================= fallback (round-1 fp32 path) =======================

__global__ void k_transpose(const float* __restrict__ emb, float* __restrict__ et) {
    int idx = blockIdx.x * blockDim.x + threadIdx.x;
    int c = idx >> 10;
    int j = idx & 1023;
    et[idx] = -2.0f * emb[j * EMBED_DIM + c];
}

__global__ __launch_bounds__(256, 2)
void k_vq(const float* __restrict__ z, const float* __restrict__ emb,
          const float* __restrict__ et, const float* __restrict__ norms,
          float* __restrict__ out, float* __restrict__ loss_acc)
{
    __shared__ float zt[EMBED_DIM * 64];
    __shared__ float redv[16 * 64];
    __shared__ int   redi[16 * 64];
    __shared__ int   widx[64];
    __shared__ float wsum[4];
    const int tid = threadIdx.x;
    const int wg  = blockIdx.x;
    const int p0  = wg * 64;
    const int b   = p0 >> 12;
    const int hw0 = p0 & 4095;
    const float* zbase = z + (size_t)b * (EMBED_DIM * HW) + hw0;
    {
        const int lane16 = tid & 15;
        const int crow   = tid >> 4;
        #pragma unroll
        for (int r = 0; r < 16; ++r) {
            int c = r * 16 + crow;
            float4 vv = *(const float4*)(zbase + (size_t)c * HW + lane16 * 4);
            *(float4*)&zt[c * 64 + lane16 * 4] = vv;
        }
    }
    __syncthreads();
    const int pxg = tid & 15;
    const int cg  = tid >> 4;
    float bestv[4] = {3.4e38f, 3.4e38f, 3.4e38f, 3.4e38f};
    int   besti[4] = {0, 0, 0, 0};
    for (int chunk = 0; chunk < 16; ++chunk) {
        const int jbase = chunk * 64 + cg * 4;
        float acc[4][4];
        #pragma unroll
        for (int i = 0; i < 4; ++i)
            #pragma unroll
            for (int k = 0; k < 4; ++k) acc[i][k] = 0.f;
        const float* ec = et + jbase;
        #pragma unroll 4
        for (int c = 0; c < EMBED_DIM; ++c) {
            float4 za = *(const float4*)&zt[c * 64 + pxg * 4];
            float4 eb = *(const float4*)(ec + (size_t)c * N_EMBED);
            float zi[4] = {za.x, za.y, za.z, za.w};
            float ek[4] = {eb.x, eb.y, eb.z, eb.w};
            #pragma unroll
            for (int i = 0; i < 4; ++i)
                #pragma unroll
                for (int k = 0; k < 4; ++k)
                    acc[i][k] += zi[i] * ek[k];
        }
        float nn[4];
        #pragma unroll
        for (int k = 0; k < 4; ++k) nn[k] = norms[jbase + k];
        #pragma unroll
        for (int i = 0; i < 4; ++i)
            #pragma unroll
            for (int k = 0; k < 4; ++k) {
                float s = nn[k] + acc[i][k];
                if (s < bestv[i]) { bestv[i] = s; besti[i] = jbase + k; }
            }
    }
    #pragma unroll
    for (int i = 0; i < 4; ++i) {
        redv[cg * 64 + pxg * 4 + i] = bestv[i];
        redi[cg * 64 + pxg * 4 + i] = besti[i];
    }
    __syncthreads();
    if (tid < 64) {
        const int px2 = tid;
        float bv = redv[px2];
        int   bi = redi[px2];
        #pragma unroll
        for (int g = 1; g < 16; ++g) {
            float vv = redv[g * 64 + px2];
            int   ix = redi[g * 64 + px2];
            if (vv < bv || (vv == bv && ix < bi)) { bv = vv; bi = ix; }
        }
        widx[px2] = bi;
    }
    __syncthreads();
    const int px = tid & 63;
    const int wv = tid >> 6;
    const int j  = widx[px];
    const float* qrow = emb + (size_t)j * EMBED_DIM;
    float* obase = out + (size_t)b * (EMBED_DIM * HW) + hw0;
    float lsum = 0.f;
    #pragma unroll 4
    for (int cc = 0; cc < 16; ++cc) {
        const int c0 = wv * 64 + cc * 4;
        float4 q = *(const float4*)(qrow + c0);
        float qv[4] = {q.x, q.y, q.z, q.w};
        #pragma unroll
        for (int k = 0; k < 4; ++k) {
            const int c = c0 + k;
            float zv = zt[c * 64 + px];
            float d = qv[k] - zv;
            lsum += d * d;
            obase[(size_t)c * HW + px] = qv[k];
        }
    }
    #pragma unroll
    for (int off = 32; off; off >>= 1) lsum += __shfl_down(lsum, off, 64);
    if ((tid & 63) == 0) wsum[wv] = lsum;
    __syncthreads();
    if (tid == 0) atomicAdd(loss_acc, wsum[0] + wsum[1] + wsum[2] + wsum[3]);
}

// ======================= launch =======================

extern "C" void kernel_launch(void* const* d_in, const int* in_sizes, int n_in,
                              void* d_out, int out_size, void* d_ws, size_t ws_size,
                              hipStream_t stream) {
    const float* z   = (const float*)d_in[0];
    const float* emb = (const float*)d_in[1];
    float* out       = (float*)d_out;
    float* ws        = (float*)d_ws;

    if (ws_size >= NEED_BYTES) {
        float*     loss_acc = ws + NW_LOSS;
        float*     norms    = ws + NW_NORMS;
        int4*      cand     = (int4*)(ws + NW_CAND);
        _Float16*  es2      = (_Float16*)(ws + NW_ES2);

        k_norms<<<N_EMBED, 64, 0, stream>>>(emb, norms, loss_acc);
        k_prep_e2<<<136, 256, 0, stream>>>(emb, norms, es2);
        k_screen4<<<256, 512, 0, stream>>>(z, es2, cand);
        k_epi<<<1024, 256, 0, stream>>>(z, emb, cand, out, loss_acc);
        k_final<<<1, 1, 0, stream>>>(loss_acc, out + (size_t)NPIX * EMBED_DIM);
    } else {
        float* loss_acc = ws;
        float* et       = ws + WS_ET_OFF;
        float* norms    = ws + WS_NORM_OFF;
        k_transpose<<<(EMBED_DIM * N_EMBED) / 256, 256, 0, stream>>>(emb, et);
        k_norms<<<N_EMBED, 64, 0, stream>>>(emb, norms, loss_acc);
        k_vq<<<NPIX / 64, 256, 0, stream>>>(z, emb, et, norms, out, loss_acc);
        k_final<<<1, 1, 0, stream>>>(loss_acc, out + (size_t)NPIX * EMBED_DIM);
    }
}